// Round 2
// baseline (200.825 us; speedup 1.0000x reference)
//
#include <hip/hip_runtime.h>
#include <cstdint>
#include <cstddef>

#define LDIM 6
#define BDIM 4
#define QDIM 900
#define CDIM 256
#define NDIM (LDIM*QDIM)   /* 5400 */
#define NN   5408          /* padded per-image stride */
#define T128 43            /* ceil(5400/128) */
#define NT128 (T128*(T128+1)/2) /* 946 lower-tri 128x128 tiles */

typedef float floatx4 __attribute__((ext_vector_type(4)));

__device__ __forceinline__ int sig_off(int b, int n) {
    int l = n / QDIM, q = n - l * QDIM;
    return ((l * BDIM + b) * QDIM + q) * CDIM;
}
__device__ __forceinline__ int logit_off(int b, int n) {
    int l = n / QDIM, q = n - l * QDIM;
    return (l * BDIM + b) * QDIM + q;
}

__device__ __forceinline__ int uf_load(const int* p, int i) {
    return __hip_atomic_load(&p[i], __ATOMIC_RELAXED, __HIP_MEMORY_SCOPE_AGENT);
}
__device__ int uf_find(int* p, int x) {
    int r = x;
    int pr = uf_load(p, r);
    while (pr != r) { r = pr; pr = uf_load(p, r); }
    return r;
}
__device__ void uf_union(int* p, int a, int b) {
    int ra = uf_find(p, a), rb = uf_find(p, b);
    while (ra != rb) {
        int hi = ra > rb ? ra : rb;
        int lo = ra ^ rb ^ hi;
        int old = atomicCAS(&p[hi], hi, lo);
        if (old == hi) return;
        ra = uf_find(p, old);
        rb = uf_find(p, lo);
    }
}

__device__ __forceinline__ int pk_fp8x4(float a, float b, float c, float d) {
    int p = __builtin_amdgcn_cvt_pk_fp8_f32(a, b, 0, false);   // bytes 0,1
    p = __builtin_amdgcn_cvt_pk_fp8_f32(c, d, p, true);        // bytes 2,3
    return p;
}

// K1: fused init + fp8 conversion. 1024 threads, 64 nodes per block.
// Wave 0: scores/parent/compKey + ballot-compacted slot claim (1 atomic per block).
// All 16 waves: convert selected rows (normalize + fp8 pack) into compacted Xf8.
// Last-done block per image: argmax fallback (only if nothing selected).
__global__ __launch_bounds__(1024) void k_prep(const float* __restrict__ logits,
                                               const float* __restrict__ sig,
                                               float* __restrict__ scores,
                                               int* __restrict__ parent,
                                               unsigned long long* __restrict__ compKey,
                                               int* __restrict__ selIdx,
                                               int* __restrict__ Mcnt,
                                               char* __restrict__ Xf8,
                                               int* __restrict__ doneP) {
    int b = blockIdx.y;
    int t = threadIdx.x;
    int lane = t & 63, wv = t >> 6;
    __shared__ int selNodeSh[64];
    __shared__ int cntSh, baseSh;
    int blockBase = blockIdx.x * 64;

    if (wv == 0) {
        int n = blockBase + lane;
        int f = 0;
        if (n < NDIM) {
            float x = logits[logit_off(b, n)];
            float sc = 1.0f / (1.0f + expf(-x));
            scores[b * NN + n] = sc;
            parent[b * NN + n] = n;
            compKey[b * NN + n] = 0ULL;
            f = (sc >= 0.5f) ? 1 : 0;
        }
        unsigned long long bal = __ballot(f != 0);
        int cnt = __popcll(bal);
        int rank = __popcll(bal & ((1ull << lane) - 1ull));
        int base = 0;
        if (lane == 0 && cnt) base = atomicAdd(&Mcnt[b], cnt);
        if (lane == 0) { cntSh = cnt; baseSh = base; }
        base = __shfl(base, 0);
        if (f) {
            selNodeSh[rank] = n;
            selIdx[b * NN + base + rank] = n;
        }
    }
    __syncthreads();

    int cnt = cntSh, base = baseSh;
    for (int i = wv; i < cnt; i += 16) {
        int node = selNodeSh[i];
        int g = base + i;
        const float4 v = *(const float4*)(sig + sig_off(b, node) + lane * 4);
        float s = v.x * v.x + v.y * v.y + v.z * v.z + v.w * v.w;
        for (int off = 32; off; off >>= 1) s += __shfl_down(s, off);
        s = __shfl(s, 0);
        float ninv = rsqrtf(s + 1e-12f);
        int p = pk_fp8x4(v.x * ninv, v.y * ninv, v.z * ninv, v.w * ninv);
        int slot = (lane >> 2) ^ (g & 15);
        *(int*)(Xf8 + ((size_t)(b * NN + g)) * 256 + slot * 16 + (lane & 3) * 4) = p;
    }

    __syncthreads();
    __shared__ int lastSh;
    if (t == 0) {
        int prev = __hip_atomic_fetch_add(&doneP[b], 1, __ATOMIC_ACQ_REL,
                                          __HIP_MEMORY_SCOPE_AGENT);
        lastSh = (prev == (int)gridDim.x - 1) ? 1 : 0;
    }
    __syncthreads();
    if (!lastSh) return;
    if (__hip_atomic_load(&Mcnt[b], __ATOMIC_RELAXED, __HIP_MEMORY_SCOPE_AGENT) != 0)
        return;

    // ---- rare fallback: nothing selected, pick argmax score ----
    __shared__ unsigned long long redSh[16];
    __shared__ int bestSh;
    unsigned long long key = 0ULL;
    for (int n = t; n < NDIM; n += 1024) {
        float sc = __hip_atomic_load(&scores[b * NN + n], __ATOMIC_RELAXED,
                                     __HIP_MEMORY_SCOPE_AGENT);
        unsigned long long k2 =
            ((unsigned long long)__float_as_uint(sc) << 32) | (unsigned int)(~n);
        if (k2 > key) key = k2;
    }
    for (int off = 32; off; off >>= 1) {
        unsigned long long o = __shfl_down(key, off);
        if (o > key) key = o;
    }
    if (lane == 0) redSh[wv] = key;
    __syncthreads();
    if (t == 0) {
        unsigned long long kk = redSh[0];
        for (int i = 1; i < 16; i++) if (redSh[i] > kk) kk = redSh[i];
        int bestNode = (int)(~(unsigned int)(kk & 0xffffffffULL));
        selIdx[b * NN + 0] = bestNode;
        __hip_atomic_store(&Mcnt[b], 1, __ATOMIC_RELAXED, __HIP_MEMORY_SCOPE_AGENT);
        bestSh = bestNode;
    }
    __syncthreads();
    if (wv == 0) {
        int node = bestSh;
        const float4 v = *(const float4*)(sig + sig_off(b, node) + lane * 4);
        float s = v.x * v.x + v.y * v.y + v.z * v.z + v.w * v.w;
        for (int off = 32; off; off >>= 1) s += __shfl_down(s, off);
        s = __shfl(s, 0);
        float ninv = rsqrtf(s + 1e-12f);
        int p = pk_fp8x4(v.x * ninv, v.y * ninv, v.z * ninv, v.w * ninv);
        int slot = (lane >> 2);   // g=0 -> no swizzle
        *(int*)(Xf8 + ((size_t)(b * NN + 0)) * 256 + slot * 16 + (lane & 3) * 4) = p;
    }
}

// K2: fp8 MFMA pairwise sims + fused component stage.
// Tile work as before; every block (active or not) increments doneS[b]; the LAST
// block of image b runs the comp stage (phase 1 union stats + ordered seed compaction)
// inside this dispatch — saves a full kernel launch+drain.
__global__ __launch_bounds__(256) void k_sim_mfma(const char* __restrict__ Xf8,
                                                  const int* __restrict__ selIdx,
                                                  const int* __restrict__ Mcnt,
                                                  int* __restrict__ parent,
                                                  const float* __restrict__ scores,
                                                  unsigned long long* __restrict__ compKey,
                                                  int* __restrict__ seedNode,
                                                  int* __restrict__ Scnt,
                                                  int* __restrict__ doneS) {
    int bx = blockIdx.x;
    int b = bx & 3;            // image -> XCD locality
    int t = bx >> 2;
    int M = Mcnt[b];
    int ti = (int)((sqrtf(8.0f * (float)t + 1.0f) - 1.0f) * 0.5f);
    while ((ti + 1) * (ti + 2) / 2 <= t) ti++;
    while (ti * (ti + 1) / 2 > t) ti--;
    int tj = t - ti * (ti + 1) / 2;
    int active = (ti * 128 < M);

    extern __shared__ char Bs[];   // 128 rows x 256 B (swizzled layout preserved)

    int tid = threadIdx.x;
    int lane = tid & 63, wave = tid >> 6;
    int rsel = lane & 15, quad = lane >> 4;

    if (active) {
        // stage B rows [tj*128, +128): 32 x 1KB contiguous copies (4 rows each)
        const char* xb = Xf8 + ((size_t)b * NN) * 256;
#pragma unroll
        for (int k = 0; k < 8; k++) {
            int i = wave * 8 + k;
            int row = min(tj * 128 + 4 * i, NN - 4);
            const char* src = xb + (size_t)row * 256 + lane * 16;
            __builtin_amdgcn_global_load_lds(
                (const __attribute__((address_space(1))) unsigned int*)src,
                (__attribute__((address_space(3))) unsigned int*)(Bs + i * 1024),
                16, 0, 0);
        }

        // A rows: wave's 32-row slab (2 x 16)
        int rA = ti * 128 + wave * 32;
        int gA0 = min(rA + rsel, M - 1);
        int gA1 = min(rA + 16 + rsel, M - 1);
        const char* pA0 = Xf8 + ((size_t)(b * NN + gA0)) * 256;
        const char* pA1 = Xf8 + ((size_t)(b * NN + gA1)) * 256;
        int swA0 = gA0 & 15, swA1 = gA1 & 15;

        __syncthreads();   // drains global_load_lds

        floatx4 acc[2][8];
#pragma unroll
        for (int s = 0; s < 2; s++)
#pragma unroll
            for (int nj = 0; nj < 8; nj++) acc[s][nj] = (floatx4){0.f, 0.f, 0.f, 0.f};

#pragma unroll
        for (int ks = 0; ks < 8; ks++) {
            int ch = ks * 2 + (quad >> 1);       // logical 16B chunk
            int ih = (quad & 1) * 8;             // 8B half within chunk
            long a0 = *(const long*)(pA0 + ((ch ^ swA0) << 4) + ih);
            long a1 = *(const long*)(pA1 + ((ch ^ swA1) << 4) + ih);
#pragma unroll
            for (int nj = 0; nj < 8; nj++) {
                int lr = nj * 16 + rsel;
                long bb = *(const long*)(Bs + lr * 256 + (((ch ^ (lr & 15)) << 4) + ih));
                acc[0][nj] = __builtin_amdgcn_mfma_f32_16x16x32_fp8_fp8(a0, bb, acc[0][nj], 0, 0, 0);
                acc[1][nj] = __builtin_amdgcn_mfma_f32_16x16x32_fp8_fp8(a1, bb, acc[1][nj], 0, 0, 0);
            }
        }

#pragma unroll
        for (int s = 0; s < 2; s++) {
            int rowA = rA + s * 16 + quad * 4;
#pragma unroll
            for (int nj = 0; nj < 8; nj++) {
                int gj = tj * 128 + nj * 16 + rsel;
#pragma unroll
                for (int r = 0; r < 4; r++) {
                    int gi = rowA + r;
                    if (gi < M && gj < M && gi > gj && acc[s][nj][r] >= 0.8f) {
                        uf_union(parent + b * NN, selIdx[b * NN + gi], selIdx[b * NN + gj]);
                    }
                }
            }
        }
    }

    // ---- done counter: last block of image b runs the comp stage ----
    __shared__ int lastSh;
    __syncthreads();
    if (tid == 0) {
        int prev = __hip_atomic_fetch_add(&doneS[b], 1, __ATOMIC_ACQ_REL,
                                          __HIP_MEMORY_SCOPE_AGENT);
        lastSh = (prev == NT128 - 1) ? 1 : 0;
    }
    __syncthreads();
    if (!lastSh) return;

    // phase 1: per selected node, find root, max packed (score, ~idx) key
    for (int g = tid; g < M; g += 256) {
        int node = selIdx[b * NN + g];
        int root = uf_find(parent + b * NN, node);
        unsigned long long key =
            ((unsigned long long)__float_as_uint(scores[b * NN + node]) << 32) |
            (unsigned int)(~node);
        atomicMax(&compKey[b * NN + root], key);
    }
    __syncthreads();

    // phase 2: ordered compaction of seeded roots. 4 waves, contiguous 1408-entry
    // ranges, 22 rounds each; pass A counts, scan, pass B scatters. Order = ascending
    // root index (wave ranges / rounds / lanes all ascending).
    __shared__ int wcnt4[4], woff4[4];
    const int RW = 22;                  /* 22*64 = 1408 >= ceil(5400/4) */
    int cnt = 0;
    for (int r = 0; r < RW; r++) {
        int n = wave * 1408 + r * 64 + lane;
        unsigned long long key = 0ULL;
        if (n < NDIM)
            key = __hip_atomic_load(&compKey[b * NN + n], __ATOMIC_RELAXED,
                                    __HIP_MEMORY_SCOPE_AGENT);
        cnt += __popcll(__ballot(key != 0ULL));
    }
    if (lane == 0) wcnt4[wave] = cnt;
    __syncthreads();
    if (tid == 0) {
        int s = 0;
        for (int i = 0; i < 4; i++) { woff4[i] = s; s += wcnt4[i]; }
        Scnt[b] = s;
    }
    __syncthreads();
    int off = woff4[wave];
    for (int r = 0; r < RW; r++) {
        int n = wave * 1408 + r * 64 + lane;
        unsigned long long key = 0ULL;
        if (n < NDIM)
            key = __hip_atomic_load(&compKey[b * NN + n], __ATOMIC_RELAXED,
                                    __HIP_MEMORY_SCOPE_AGENT);
        unsigned long long bal = __ballot(key != 0ULL);
        int rank = __popcll(bal & ((1ull << lane) - 1ull));
        if (key != 0ULL)
            seedNode[b * NN + off + rank] = (int)(~(unsigned int)(key & 0xffffffffULL));
        off += __popcll(bal);
    }
}

// K3: write seed signatures / mask / scores; zero-fill empty slots. 4 rows per block.
__global__ void k_write(const float* __restrict__ sig, const float* __restrict__ scores,
                        const int* __restrict__ seedNode, const int* __restrict__ Scnt,
                        float* __restrict__ out) {
    int b = blockIdx.y;
    int slot = blockIdx.x * 4 + (threadIdx.x >> 6);
    int lane = threadIdx.x & 63;
    float* orow = out + ((size_t)(b * NDIM + slot)) * CDIM + lane * 4;
    if (slot < Scnt[b]) {
        int s = seedNode[b * NN + slot];
        float4 v = *(const float4*)(sig + sig_off(b, s) + lane * 4);
        *(float4*)orow = v;
        if (lane == 0) {
            out[(size_t)BDIM * NDIM * CDIM + (size_t)b * NDIM + slot] = 1.0f;
            out[(size_t)BDIM * NDIM * CDIM + (size_t)BDIM * NDIM + (size_t)b * NDIM + slot] =
                scores[b * NN + s];
        }
    } else {
        float4 z = {0.f, 0.f, 0.f, 0.f};
        *(float4*)orow = z;
        if (lane == 0) {
            out[(size_t)BDIM * NDIM * CDIM + (size_t)b * NDIM + slot] = 0.0f;
            out[(size_t)BDIM * NDIM * CDIM + (size_t)BDIM * NDIM + (size_t)b * NDIM + slot] = 0.0f;
        }
    }
}

extern "C" void kernel_launch(void* const* d_in, const int* in_sizes, int n_in,
                              void* d_out, int out_size, void* d_ws, size_t ws_size,
                              hipStream_t stream) {
    (void)in_sizes; (void)n_in; (void)out_size; (void)ws_size;
    const float* sig = (const float*)d_in[0];
    const float* logits = (const float*)d_in[1];
    float* out = (float*)d_out;
    char* ws = (char*)d_ws;

    const size_t arr = (size_t)BDIM * NN * 4;  // 86528 B per int/float array
    int* Mcnt = (int*)(ws + 0);                       // 16 B
    int* Scnt = (int*)(ws + 64);                      // 16 B
    int* doneP = (int*)(ws + 128);                    // 16 B
    int* doneS = (int*)(ws + 192);                    // 16 B
    unsigned long long* compKey = (unsigned long long*)(ws + 256); // 2*arr
    float* scores = (float*)(ws + 256 + 2 * arr);
    int* parent   = (int*)(ws + 256 + 3 * arr);
    int* selIdx   = (int*)(ws + 256 + 4 * arr);
    int* seedNode = (int*)(ws + 256 + 5 * arr);
    char* Xf8     = (char*)(ws + 256 + 6 * arr);      // BDIM*NN*256 = 5.5 MB

    hipMemsetAsync(ws, 0, 512, stream);   // header: Mcnt/Scnt/doneP/doneS

    k_prep<<<dim3((NDIM + 63) / 64, BDIM), 1024, 0, stream>>>(
        logits, sig, scores, parent, compKey, selIdx, Mcnt, Xf8, doneP);
    k_sim_mfma<<<NT128 * BDIM, 256, 32768, stream>>>(
        Xf8, selIdx, Mcnt, parent, scores, compKey, seedNode, Scnt, doneS);
    k_write<<<dim3(NDIM / 4, BDIM), 256, 0, stream>>>(sig, scores, seedNode, Scnt, out);
}

// Round 3
// 114.537 us; speedup vs baseline: 1.7534x; 1.7534x over previous
//
#include <hip/hip_runtime.h>
#include <cstdint>
#include <cstddef>

#define LDIM 6
#define BDIM 4
#define QDIM 900
#define CDIM 256
#define NDIM (LDIM*QDIM)   /* 5400 */
#define NN   5408          /* padded per-image stride */
#define T128 43            /* ceil(5400/128) */
#define NT128 (T128*(T128+1)/2) /* 946 lower-tri 128x128 tiles */

typedef float floatx4 __attribute__((ext_vector_type(4)));

__device__ __forceinline__ int sig_off(int b, int n) {
    int l = n / QDIM, q = n - l * QDIM;
    return ((l * BDIM + b) * QDIM + q) * CDIM;
}
__device__ __forceinline__ int logit_off(int b, int n) {
    int l = n / QDIM, q = n - l * QDIM;
    return (l * BDIM + b) * QDIM + q;
}

__device__ __forceinline__ int uf_load(const int* p, int i) {
    return __hip_atomic_load(&p[i], __ATOMIC_RELAXED, __HIP_MEMORY_SCOPE_AGENT);
}
__device__ int uf_find(int* p, int x) {
    int r = x;
    int pr = uf_load(p, r);
    while (pr != r) { r = pr; pr = uf_load(p, r); }
    return r;
}
__device__ void uf_union(int* p, int a, int b) {
    int ra = uf_find(p, a), rb = uf_find(p, b);
    while (ra != rb) {
        int hi = ra > rb ? ra : rb;
        int lo = ra ^ rb ^ hi;
        int old = atomicCAS(&p[hi], hi, lo);
        if (old == hi) return;
        ra = uf_find(p, old);
        rb = uf_find(p, lo);
    }
}

__device__ __forceinline__ int pk_fp8x4(float a, float b, float c, float d) {
    int p = __builtin_amdgcn_cvt_pk_fp8_f32(a, b, 0, false);   // bytes 0,1
    p = __builtin_amdgcn_cvt_pk_fp8_f32(c, d, p, true);        // bytes 2,3
    return p;
}

// K1: fused init + fp8 conversion. 1024 threads, 64 nodes per block.
// Wave 0: scores/parent/compKey + ballot-compacted slot claim (1 atomic per block).
// All 16 waves: convert selected rows (normalize + fp8 pack) into compacted Xf8.
// Last-done block per image: argmax fallback (only if nothing selected).
__global__ __launch_bounds__(1024) void k_prep(const float* __restrict__ logits,
                                               const float* __restrict__ sig,
                                               float* __restrict__ scores,
                                               int* __restrict__ parent,
                                               unsigned long long* __restrict__ compKey,
                                               int* __restrict__ selIdx,
                                               int* __restrict__ Mcnt,
                                               char* __restrict__ Xf8,
                                               int* __restrict__ doneP) {
    int b = blockIdx.y;
    int t = threadIdx.x;
    int lane = t & 63, wv = t >> 6;
    __shared__ int selNodeSh[64];
    __shared__ int cntSh, baseSh;
    int blockBase = blockIdx.x * 64;

    if (wv == 0) {
        int n = blockBase + lane;
        int f = 0;
        if (n < NDIM) {
            float x = logits[logit_off(b, n)];
            float sc = 1.0f / (1.0f + expf(-x));
            scores[b * NN + n] = sc;
            parent[b * NN + n] = n;
            compKey[b * NN + n] = 0ULL;
            f = (sc >= 0.5f) ? 1 : 0;
        }
        unsigned long long bal = __ballot(f != 0);
        int cnt = __popcll(bal);
        int rank = __popcll(bal & ((1ull << lane) - 1ull));
        int base = 0;
        if (lane == 0 && cnt) base = atomicAdd(&Mcnt[b], cnt);
        if (lane == 0) { cntSh = cnt; baseSh = base; }
        base = __shfl(base, 0);
        if (f) {
            selNodeSh[rank] = n;
            selIdx[b * NN + base + rank] = n;
        }
    }
    __syncthreads();

    int cnt = cntSh, base = baseSh;
    for (int i = wv; i < cnt; i += 16) {
        int node = selNodeSh[i];
        int g = base + i;
        const float4 v = *(const float4*)(sig + sig_off(b, node) + lane * 4);
        float s = v.x * v.x + v.y * v.y + v.z * v.z + v.w * v.w;
        for (int off = 32; off; off >>= 1) s += __shfl_down(s, off);
        s = __shfl(s, 0);
        float ninv = rsqrtf(s + 1e-12f);
        int p = pk_fp8x4(v.x * ninv, v.y * ninv, v.z * ninv, v.w * ninv);
        int slot = (lane >> 2) ^ (g & 15);
        *(int*)(Xf8 + ((size_t)(b * NN + g)) * 256 + slot * 16 + (lane & 3) * 4) = p;
    }

    __syncthreads();
    __shared__ int lastSh;
    if (t == 0) {
        int prev = __hip_atomic_fetch_add(&doneP[b], 1, __ATOMIC_ACQ_REL,
                                          __HIP_MEMORY_SCOPE_AGENT);
        lastSh = (prev == (int)gridDim.x - 1) ? 1 : 0;
    }
    __syncthreads();
    if (!lastSh) return;
    if (__hip_atomic_load(&Mcnt[b], __ATOMIC_RELAXED, __HIP_MEMORY_SCOPE_AGENT) != 0)
        return;

    // ---- rare fallback: nothing selected, pick argmax score ----
    __shared__ unsigned long long redSh[16];
    __shared__ int bestSh;
    unsigned long long key = 0ULL;
    for (int n = t; n < NDIM; n += 1024) {
        float sc = __hip_atomic_load(&scores[b * NN + n], __ATOMIC_RELAXED,
                                     __HIP_MEMORY_SCOPE_AGENT);
        unsigned long long k2 =
            ((unsigned long long)__float_as_uint(sc) << 32) | (unsigned int)(~n);
        if (k2 > key) key = k2;
    }
    for (int off = 32; off; off >>= 1) {
        unsigned long long o = __shfl_down(key, off);
        if (o > key) key = o;
    }
    if (lane == 0) redSh[wv] = key;
    __syncthreads();
    if (t == 0) {
        unsigned long long kk = redSh[0];
        for (int i = 1; i < 16; i++) if (redSh[i] > kk) kk = redSh[i];
        int bestNode = (int)(~(unsigned int)(kk & 0xffffffffULL));
        selIdx[b * NN + 0] = bestNode;
        __hip_atomic_store(&Mcnt[b], 1, __ATOMIC_RELAXED, __HIP_MEMORY_SCOPE_AGENT);
        bestSh = bestNode;
    }
    __syncthreads();
    if (wv == 0) {
        int node = bestSh;
        const float4 v = *(const float4*)(sig + sig_off(b, node) + lane * 4);
        float s = v.x * v.x + v.y * v.y + v.z * v.z + v.w * v.w;
        for (int off = 32; off; off >>= 1) s += __shfl_down(s, off);
        s = __shfl(s, 0);
        float ninv = rsqrtf(s + 1e-12f);
        int p = pk_fp8x4(v.x * ninv, v.y * ninv, v.z * ninv, v.w * ninv);
        int slot = (lane >> 2);   // g=0 -> no swizzle
        *(int*)(Xf8 + ((size_t)(b * NN + 0)) * 256 + slot * 16 + (lane & 3) * 4) = p;
    }
}

// K2: fp8 MFMA pairwise sims, 128x128 tiles (R1 form: early return, no fused tail).
// B tile (128 rows, 32 KB) staged to LDS; A rows direct from global.
__global__ __launch_bounds__(256) void k_sim_mfma(const char* __restrict__ Xf8,
                                                  const int* __restrict__ selIdx,
                                                  const int* __restrict__ Mcnt,
                                                  int* __restrict__ parent) {
    int bx = blockIdx.x;
    int b = bx & 3;            // image -> XCD locality
    int t = bx >> 2;
    int M = Mcnt[b];
    int ti = (int)((sqrtf(8.0f * (float)t + 1.0f) - 1.0f) * 0.5f);
    while ((ti + 1) * (ti + 2) / 2 <= t) ti++;
    while (ti * (ti + 1) / 2 > t) ti--;
    int tj = t - ti * (ti + 1) / 2;
    if (ti * 128 >= M) return;

    extern __shared__ char Bs[];   // 128 rows x 256 B (swizzled layout preserved)

    int tid = threadIdx.x;
    int lane = tid & 63, wave = tid >> 6;
    int rsel = lane & 15, quad = lane >> 4;

    // stage B rows [tj*128, +128): 32 x 1KB contiguous copies (4 rows each), 8 per wave
    const char* xb = Xf8 + ((size_t)b * NN) * 256;
#pragma unroll
    for (int k = 0; k < 8; k++) {
        int i = wave * 8 + k;
        int row = min(tj * 128 + 4 * i, NN - 4);
        const char* src = xb + (size_t)row * 256 + lane * 16;
        __builtin_amdgcn_global_load_lds(
            (const __attribute__((address_space(1))) unsigned int*)src,
            (__attribute__((address_space(3))) unsigned int*)(Bs + i * 1024),
            16, 0, 0);
    }

    // A rows: wave's 32-row slab (2 x 16)
    int rA = ti * 128 + wave * 32;
    int gA0 = min(rA + rsel, M - 1);
    int gA1 = min(rA + 16 + rsel, M - 1);
    const char* pA0 = Xf8 + ((size_t)(b * NN + gA0)) * 256;
    const char* pA1 = Xf8 + ((size_t)(b * NN + gA1)) * 256;
    int swA0 = gA0 & 15, swA1 = gA1 & 15;

    __syncthreads();   // drains global_load_lds

    floatx4 acc[2][8];
#pragma unroll
    for (int s = 0; s < 2; s++)
#pragma unroll
        for (int nj = 0; nj < 8; nj++) acc[s][nj] = (floatx4){0.f, 0.f, 0.f, 0.f};

#pragma unroll
    for (int ks = 0; ks < 8; ks++) {
        int ch = ks * 2 + (quad >> 1);       // logical 16B chunk of the 32B K-slab half
        int ih = (quad & 1) * 8;             // 8B half within chunk
        long a0 = *(const long*)(pA0 + ((ch ^ swA0) << 4) + ih);
        long a1 = *(const long*)(pA1 + ((ch ^ swA1) << 4) + ih);
#pragma unroll
        for (int nj = 0; nj < 8; nj++) {
            int lr = nj * 16 + rsel;
            long bb = *(const long*)(Bs + lr * 256 + (((ch ^ (lr & 15)) << 4) + ih));
            acc[0][nj] = __builtin_amdgcn_mfma_f32_16x16x32_fp8_fp8(a0, bb, acc[0][nj], 0, 0, 0);
            acc[1][nj] = __builtin_amdgcn_mfma_f32_16x16x32_fp8_fp8(a1, bb, acc[1][nj], 0, 0, 0);
        }
    }

#pragma unroll
    for (int s = 0; s < 2; s++) {
        int rowA = rA + s * 16 + quad * 4;
#pragma unroll
        for (int nj = 0; nj < 8; nj++) {
            int gj = tj * 128 + nj * 16 + rsel;
#pragma unroll
            for (int r = 0; r < 4; r++) {
                int gi = rowA + r;
                if (gi < M && gj < M && gi > gj && acc[s][nj][r] >= 0.8f) {
                    uf_union(parent + b * NN, selIdx[b * NN + gi], selIdx[b * NN + gj]);
                }
            }
        }
    }
}

// K3: component stats + ranking. One 1024-thr block per image (R1 form:
// 16 parallel wave ranges, register-cached keys, 2 syncthreads total).
__global__ __launch_bounds__(1024) void k_comp(int* __restrict__ parent,
                                               const int* __restrict__ selIdx,
                                               const int* __restrict__ Mcnt,
                                               const float* __restrict__ scores,
                                               unsigned long long* __restrict__ compKey,
                                               int* __restrict__ seedNode,
                                               int* __restrict__ Scnt) {
    int b = blockIdx.x, t = threadIdx.x;
    int lane = t & 63, w = t >> 6;      // 16 waves
    __shared__ int wcnt[16];
    __shared__ int woff[16];

    // phase 1: per selected node, find root, max packed (score, ~idx) key
    int M = Mcnt[b];
    for (int base = 0; base < M; base += 1024) {
        int g = base + t;
        if (g < M) {
            int node = selIdx[b * NN + g];
            int root = uf_find(parent + b * NN, node);
            unsigned long long key =
                ((unsigned long long)__float_as_uint(scores[b * NN + node]) << 32) |
                (unsigned int)(~node);
            atomicMax(&compKey[b * NN + root], key);
        }
    }
    __syncthreads();

    // phase 2 pass A: each wave counts seeded roots in its 384-entry range,
    // caching keys in registers (agent-scope loads to bypass stale L1).
#define CROUNDS 6   /* 16 waves * 6 rounds * 64 lanes = 6144 >= NDIM */
    unsigned long long kc[CROUNDS];
    int cnt = 0;
#pragma unroll
    for (int r = 0; r < CROUNDS; r++) {
        int n = (w * CROUNDS + r) * 64 + lane;
        unsigned long long key = 0ULL;
        if (n < NDIM)
            key = __hip_atomic_load(&compKey[b * NN + n], __ATOMIC_RELAXED,
                                    __HIP_MEMORY_SCOPE_AGENT);
        kc[r] = key;
        cnt += __popcll(__ballot(key != 0ULL));
    }
    if (lane == 0) wcnt[w] = cnt;
    __syncthreads();
    if (t == 0) {
        int s = 0;
        for (int i = 0; i < 16; i++) { int v = wcnt[i]; woff[i] = s; s += v; }
        Scnt[b] = s;
    }
    __syncthreads();

    // phase 2 pass B: scatter seeds at exclusive-scanned offsets, order preserved.
    int off = woff[w];
#pragma unroll
    for (int r = 0; r < CROUNDS; r++) {
        unsigned long long bal = __ballot(kc[r] != 0ULL);
        int rank = __popcll(bal & ((1ull << lane) - 1ull));
        if (kc[r] != 0ULL)
            seedNode[b * NN + off + rank] =
                (int)(~(unsigned int)(kc[r] & 0xffffffffULL));
        off += __popcll(bal);
    }
#undef CROUNDS
}

// K4: write seed signatures / mask / scores; zero-fill empty slots. 4 rows per block.
__global__ void k_write(const float* __restrict__ sig, const float* __restrict__ scores,
                        const int* __restrict__ seedNode, const int* __restrict__ Scnt,
                        float* __restrict__ out) {
    int b = blockIdx.y;
    int slot = blockIdx.x * 4 + (threadIdx.x >> 6);
    int lane = threadIdx.x & 63;
    float* orow = out + ((size_t)(b * NDIM + slot)) * CDIM + lane * 4;
    if (slot < Scnt[b]) {
        int s = seedNode[b * NN + slot];
        float4 v = *(const float4*)(sig + sig_off(b, s) + lane * 4);
        *(float4*)orow = v;
        if (lane == 0) {
            out[(size_t)BDIM * NDIM * CDIM + (size_t)b * NDIM + slot] = 1.0f;
            out[(size_t)BDIM * NDIM * CDIM + (size_t)BDIM * NDIM + (size_t)b * NDIM + slot] =
                scores[b * NN + s];
        }
    } else {
        float4 z = {0.f, 0.f, 0.f, 0.f};
        *(float4*)orow = z;
        if (lane == 0) {
            out[(size_t)BDIM * NDIM * CDIM + (size_t)b * NDIM + slot] = 0.0f;
            out[(size_t)BDIM * NDIM * CDIM + (size_t)BDIM * NDIM + (size_t)b * NDIM + slot] = 0.0f;
        }
    }
}

extern "C" void kernel_launch(void* const* d_in, const int* in_sizes, int n_in,
                              void* d_out, int out_size, void* d_ws, size_t ws_size,
                              hipStream_t stream) {
    (void)in_sizes; (void)n_in; (void)out_size; (void)ws_size;
    const float* sig = (const float*)d_in[0];
    const float* logits = (const float*)d_in[1];
    float* out = (float*)d_out;
    char* ws = (char*)d_ws;

    const size_t arr = (size_t)BDIM * NN * 4;  // 86528 B per int/float array
    int* Mcnt = (int*)(ws + 0);                       // 16 B
    int* Scnt = (int*)(ws + 64);                      // 16 B
    int* doneP = (int*)(ws + 128);                    // 16 B
    unsigned long long* compKey = (unsigned long long*)(ws + 256); // 2*arr
    float* scores = (float*)(ws + 256 + 2 * arr);
    int* parent   = (int*)(ws + 256 + 3 * arr);
    int* selIdx   = (int*)(ws + 256 + 4 * arr);
    int* seedNode = (int*)(ws + 256 + 5 * arr);
    char* Xf8     = (char*)(ws + 256 + 6 * arr);      // BDIM*NN*256 = 5.5 MB

    hipMemsetAsync(ws, 0, 512, stream);   // header: Mcnt/Scnt/doneP

    k_prep<<<dim3((NDIM + 63) / 64, BDIM), 1024, 0, stream>>>(
        logits, sig, scores, parent, compKey, selIdx, Mcnt, Xf8, doneP);
    k_sim_mfma<<<NT128 * BDIM, 256, 32768, stream>>>(Xf8, selIdx, Mcnt, parent);
    k_comp<<<BDIM, 1024, 0, stream>>>(parent, selIdx, Mcnt, scores, compKey, seedNode, Scnt);
    k_write<<<dim3(NDIM / 4, BDIM), 256, 0, stream>>>(sig, scores, seedNode, Scnt, out);
}

// Round 4
// 105.538 us; speedup vs baseline: 1.9029x; 1.0853x over previous
//
#include <hip/hip_runtime.h>
#include <cstdint>
#include <cstddef>

#define LDIM 6
#define BDIM 4
#define QDIM 900
#define CDIM 256
#define NDIM (LDIM*QDIM)   /* 5400 */
#define NN   5408          /* padded per-image stride */
#define T128 43            /* ceil(5400/128) */
#define NT128 (T128*(T128+1)/2) /* 946 lower-tri 128x128 tiles */

/* per-image header slots padded to one 64B cache line each to avoid
   same-line atomic serialization across blocks/images */
#define HS4 16   /* stride in ints   (64 B) */
#define HS8 8    /* stride in u64    (64 B) */

typedef float floatx4 __attribute__((ext_vector_type(4)));

__device__ __forceinline__ int sig_off(int b, int n) {
    int l = n / QDIM, q = n - l * QDIM;
    return ((l * BDIM + b) * QDIM + q) * CDIM;
}
__device__ __forceinline__ int logit_off(int b, int n) {
    int l = n / QDIM, q = n - l * QDIM;
    return (l * BDIM + b) * QDIM + q;
}

__device__ __forceinline__ int uf_load(const int* p, int i) {
    return __hip_atomic_load(&p[i], __ATOMIC_RELAXED, __HIP_MEMORY_SCOPE_AGENT);
}
__device__ int uf_find(int* p, int x) {
    int r = x;
    int pr = uf_load(p, r);
    while (pr != r) { r = pr; pr = uf_load(p, r); }
    return r;
}
__device__ void uf_union(int* p, int a, int b) {
    int ra = uf_find(p, a), rb = uf_find(p, b);
    while (ra != rb) {
        int hi = ra > rb ? ra : rb;
        int lo = ra ^ rb ^ hi;
        int old = atomicCAS(&p[hi], hi, lo);
        if (old == hi) return;
        ra = uf_find(p, old);
        rb = uf_find(p, lo);
    }
}

__device__ __forceinline__ int pk_fp8x4(float a, float b, float c, float d) {
    int p = __builtin_amdgcn_cvt_pk_fp8_f32(a, b, 0, false);   // bytes 0,1
    p = __builtin_amdgcn_cvt_pk_fp8_f32(c, d, p, true);        // bytes 2,3
    return p;
}

// K1: wide init — scores, parent, compKey=0, UNORDERED selIdx compaction (per-wave
// atomic slot claim), per-image argmax key, last-block argmax fallback.
__global__ void k_init(const float* __restrict__ logits, float* __restrict__ scores,
                       int* __restrict__ parent, unsigned long long* __restrict__ compKey,
                       int* __restrict__ selIdx, int* __restrict__ Mcnt,
                       unsigned long long* __restrict__ argKey, int* __restrict__ done) {
    int b = blockIdx.y;
    int n = blockIdx.x * 256 + threadIdx.x;
    int lane = threadIdx.x & 63;
    if (n < NN) compKey[b * NN + n] = 0ULL;
    unsigned long long key = 0ULL;
    int f = 0;
    if (n < NDIM) {
        float x = logits[logit_off(b, n)];
        float sc = 1.0f / (1.0f + expf(-x));
        scores[b * NN + n] = sc;
        parent[b * NN + n] = n;
        f = (sc >= 0.5f) ? 1 : 0;
        key = ((unsigned long long)__float_as_uint(sc) << 32) | (unsigned int)(~n);
    }
    unsigned long long bal = __ballot(f != 0);
    int cnt = __popcll(bal);
    int rank = __popcll(bal & ((1ull << lane) - 1ull));
    int base = 0;
    if (lane == 0 && cnt) base = atomicAdd(&Mcnt[b * HS4], cnt);
    base = __shfl(base, 0);
    if (f) selIdx[b * NN + base + rank] = n;
    // wave argmax -> global
    for (int off = 32; off; off >>= 1) {
        unsigned long long o = __shfl_down(key, off);
        if (o > key) key = o;
    }
    if (lane == 0) atomicMax(&argKey[b * HS8], key);
    __syncthreads();
    if (threadIdx.x == 0) {
        int prev = __hip_atomic_fetch_add(&done[b * HS4], 1, __ATOMIC_ACQ_REL,
                                          __HIP_MEMORY_SCOPE_AGENT);
        if (prev == (int)gridDim.x - 1) {   // last block: fallback if nothing selected
            if (__hip_atomic_load(&Mcnt[b * HS4], __ATOMIC_RELAXED,
                                  __HIP_MEMORY_SCOPE_AGENT) == 0) {
                unsigned long long k = __hip_atomic_load(&argKey[b * HS8], __ATOMIC_RELAXED,
                                                         __HIP_MEMORY_SCOPE_AGENT);
                selIdx[b * NN + 0] = (int)(~(unsigned int)(k & 0xffffffffULL));
                __hip_atomic_store(&Mcnt[b * HS4], 1, __ATOMIC_RELAXED,
                                   __HIP_MEMORY_SCOPE_AGENT);
            }
        }
    }
}

// K2: normalize + fp32->fp8(e4m3) compaction. Row = 256 B = 16 chunks of 16 B;
// chunk c stored at slot c ^ (g & 15). One wave per row.
__global__ void k_tobf(const float* __restrict__ sig, const int* __restrict__ selIdx,
                       const int* __restrict__ Mcnt, char* __restrict__ Xf8) {
    int b = blockIdx.y;
    int g = (blockIdx.x * blockDim.x + threadIdx.x) >> 6;
    int lane = threadIdx.x & 63;
    if (g >= Mcnt[b * HS4]) return;
    int node = selIdx[b * NN + g];
    const float4 v = *(const float4*)(sig + sig_off(b, node) + lane * 4);
    float s = v.x * v.x + v.y * v.y + v.z * v.z + v.w * v.w;
    for (int off = 32; off; off >>= 1) s += __shfl_down(s, off);
    s = __shfl(s, 0);
    float ninv = rsqrtf(s + 1e-12f);
    int p = pk_fp8x4(v.x * ninv, v.y * ninv, v.z * ninv, v.w * ninv);
    int slot = (lane >> 2) ^ (g & 15);
    *(int*)(Xf8 + ((size_t)(b * NN + g)) * 256 + slot * 16 + (lane & 3) * 4) = p;
}

// K3: fp8 MFMA pairwise sims, 128x128 tiles. B tile (128 rows, 32 KB) staged to LDS;
// A rows direct from global. 16 MFMA per K-step per wave.
__global__ __launch_bounds__(256) void k_sim_mfma(const char* __restrict__ Xf8,
                                                  const int* __restrict__ selIdx,
                                                  const int* __restrict__ Mcnt,
                                                  int* __restrict__ parent) {
    int bx = blockIdx.x;
    int b = bx & 3;            // image -> XCD locality
    int t = bx >> 2;
    int M = Mcnt[b * HS4];
    int ti = (int)((sqrtf(8.0f * (float)t + 1.0f) - 1.0f) * 0.5f);
    while ((ti + 1) * (ti + 2) / 2 <= t) ti++;
    while (ti * (ti + 1) / 2 > t) ti--;
    int tj = t - ti * (ti + 1) / 2;
    if (ti * 128 >= M) return;

    extern __shared__ char Bs[];   // 128 rows x 256 B (swizzled layout preserved)

    int tid = threadIdx.x;
    int lane = tid & 63, wave = tid >> 6;
    int rsel = lane & 15, quad = lane >> 4;

    // stage B rows [tj*128, +128): 32 x 1KB contiguous copies (4 rows each), 8 per wave
    const char* xb = Xf8 + ((size_t)b * NN) * 256;
#pragma unroll
    for (int k = 0; k < 8; k++) {
        int i = wave * 8 + k;
        int row = min(tj * 128 + 4 * i, NN - 4);
        const char* src = xb + (size_t)row * 256 + lane * 16;
        __builtin_amdgcn_global_load_lds(
            (const __attribute__((address_space(1))) unsigned int*)src,
            (__attribute__((address_space(3))) unsigned int*)(Bs + i * 1024),
            16, 0, 0);
    }

    // A rows: wave's 32-row slab (2 x 16)
    int rA = ti * 128 + wave * 32;
    int gA0 = min(rA + rsel, M - 1);
    int gA1 = min(rA + 16 + rsel, M - 1);
    const char* pA0 = Xf8 + ((size_t)(b * NN + gA0)) * 256;
    const char* pA1 = Xf8 + ((size_t)(b * NN + gA1)) * 256;
    int swA0 = gA0 & 15, swA1 = gA1 & 15;

    __syncthreads();   // drains global_load_lds

    floatx4 acc[2][8];
#pragma unroll
    for (int s = 0; s < 2; s++)
#pragma unroll
        for (int nj = 0; nj < 8; nj++) acc[s][nj] = (floatx4){0.f, 0.f, 0.f, 0.f};

#pragma unroll
    for (int ks = 0; ks < 8; ks++) {
        int ch = ks * 2 + (quad >> 1);       // logical 16B chunk of the 32B K-slab half
        int ih = (quad & 1) * 8;             // 8B half within chunk
        long a0 = *(const long*)(pA0 + ((ch ^ swA0) << 4) + ih);
        long a1 = *(const long*)(pA1 + ((ch ^ swA1) << 4) + ih);
#pragma unroll
        for (int nj = 0; nj < 8; nj++) {
            int lr = nj * 16 + rsel;
            long bb = *(const long*)(Bs + lr * 256 + (((ch ^ (lr & 15)) << 4) + ih));
            acc[0][nj] = __builtin_amdgcn_mfma_f32_16x16x32_fp8_fp8(a0, bb, acc[0][nj], 0, 0, 0);
            acc[1][nj] = __builtin_amdgcn_mfma_f32_16x16x32_fp8_fp8(a1, bb, acc[1][nj], 0, 0, 0);
        }
    }

#pragma unroll
    for (int s = 0; s < 2; s++) {
        int rowA = rA + s * 16 + quad * 4;
#pragma unroll
        for (int nj = 0; nj < 8; nj++) {
            int gj = tj * 128 + nj * 16 + rsel;
#pragma unroll
            for (int r = 0; r < 4; r++) {
                int gi = rowA + r;
                if (gi < M && gj < M && gi > gj && acc[s][nj][r] >= 0.8f) {
                    uf_union(parent + b * NN, selIdx[b * NN + gi], selIdx[b * NN + gj]);
                }
            }
        }
    }
}

// K4: component stats + ranking. One 1024-thr block per image.
// 16 parallel wave ranges, register-cached keys, 2 syncthreads total.
__global__ __launch_bounds__(1024) void k_comp(int* __restrict__ parent,
                                               const int* __restrict__ selIdx,
                                               const int* __restrict__ Mcnt,
                                               const float* __restrict__ scores,
                                               unsigned long long* __restrict__ compKey,
                                               int* __restrict__ seedNode,
                                               int* __restrict__ Scnt) {
    int b = blockIdx.x, t = threadIdx.x;
    int lane = t & 63, w = t >> 6;      // 16 waves
    __shared__ int wcnt[16];
    __shared__ int woff[16];

    // phase 1: per selected node, find root, max packed (score, ~idx) key
    int M = Mcnt[b * HS4];
    for (int base = 0; base < M; base += 1024) {
        int g = base + t;
        if (g < M) {
            int node = selIdx[b * NN + g];
            int root = uf_find(parent + b * NN, node);
            unsigned long long key =
                ((unsigned long long)__float_as_uint(scores[b * NN + node]) << 32) |
                (unsigned int)(~node);
            atomicMax(&compKey[b * NN + root], key);
        }
    }
    __syncthreads();

    // phase 2 pass A: each wave counts seeded roots in its 384-entry range,
    // caching keys in registers (agent-scope loads to bypass stale L1).
#define CROUNDS 6   /* 16 waves * 6 rounds * 64 lanes = 6144 >= NDIM */
    unsigned long long kc[CROUNDS];
    int cnt = 0;
#pragma unroll
    for (int r = 0; r < CROUNDS; r++) {
        int n = (w * CROUNDS + r) * 64 + lane;
        unsigned long long key = 0ULL;
        if (n < NDIM)
            key = __hip_atomic_load(&compKey[b * NN + n], __ATOMIC_RELAXED,
                                    __HIP_MEMORY_SCOPE_AGENT);
        kc[r] = key;
        cnt += __popcll(__ballot(key != 0ULL));
    }
    if (lane == 0) wcnt[w] = cnt;
    __syncthreads();
    if (t == 0) {
        int s = 0;
        for (int i = 0; i < 16; i++) { int v = wcnt[i]; woff[i] = s; s += v; }
        Scnt[b * HS4] = s;
    }
    __syncthreads();

    // phase 2 pass B: scatter seeds at exclusive-scanned offsets, order preserved.
    int off = woff[w];
#pragma unroll
    for (int r = 0; r < CROUNDS; r++) {
        unsigned long long bal = __ballot(kc[r] != 0ULL);
        int rank = __popcll(bal & ((1ull << lane) - 1ull));
        if (kc[r] != 0ULL)
            seedNode[b * NN + off + rank] =
                (int)(~(unsigned int)(kc[r] & 0xffffffffULL));
        off += __popcll(bal);
    }
#undef CROUNDS
}

// K5: write seed signatures / mask / scores; zero-fill empty slots. 4 rows per block.
__global__ void k_write(const float* __restrict__ sig, const float* __restrict__ scores,
                        const int* __restrict__ seedNode, const int* __restrict__ Scnt,
                        float* __restrict__ out) {
    int b = blockIdx.y;
    int slot = blockIdx.x * 4 + (threadIdx.x >> 6);
    int lane = threadIdx.x & 63;
    float* orow = out + ((size_t)(b * NDIM + slot)) * CDIM + lane * 4;
    if (slot < Scnt[b * HS4]) {
        int s = seedNode[b * NN + slot];
        float4 v = *(const float4*)(sig + sig_off(b, s) + lane * 4);
        *(float4*)orow = v;
        if (lane == 0) {
            out[(size_t)BDIM * NDIM * CDIM + (size_t)b * NDIM + slot] = 1.0f;
            out[(size_t)BDIM * NDIM * CDIM + (size_t)BDIM * NDIM + (size_t)b * NDIM + slot] =
                scores[b * NN + s];
        }
    } else {
        float4 z = {0.f, 0.f, 0.f, 0.f};
        *(float4*)orow = z;
        if (lane == 0) {
            out[(size_t)BDIM * NDIM * CDIM + (size_t)b * NDIM + slot] = 0.0f;
            out[(size_t)BDIM * NDIM * CDIM + (size_t)BDIM * NDIM + (size_t)b * NDIM + slot] = 0.0f;
        }
    }
}

extern "C" void kernel_launch(void* const* d_in, const int* in_sizes, int n_in,
                              void* d_out, int out_size, void* d_ws, size_t ws_size,
                              hipStream_t stream) {
    (void)in_sizes; (void)n_in; (void)out_size; (void)ws_size;
    const float* sig = (const float*)d_in[0];
    const float* logits = (const float*)d_in[1];
    float* out = (float*)d_out;
    char* ws = (char*)d_ws;

    // header: 4 arrays x 4 images x 64B/line = 1024 B
    int* Mcnt = (int*)(ws + 0);                        // [b*HS4], 256 B
    int* done = (int*)(ws + 256);                      // [b*HS4], 256 B
    unsigned long long* argKey = (unsigned long long*)(ws + 512);  // [b*HS8], 256 B
    int* Scnt = (int*)(ws + 768);                      // [b*HS4], 256 B

    const size_t arr = (size_t)BDIM * NN * 4;  // 86528 B per int/float array
    unsigned long long* compKey = (unsigned long long*)(ws + 1024); // 2*arr
    float* scores = (float*)(ws + 1024 + 2 * arr);
    int* parent   = (int*)(ws + 1024 + 3 * arr);
    int* selIdx   = (int*)(ws + 1024 + 4 * arr);
    int* seedNode = (int*)(ws + 1024 + 5 * arr);
    char* Xf8     = (char*)(ws + 1024 + 6 * arr);      // BDIM*NN*256 = 5.5 MB

    hipMemsetAsync(ws, 0, 1024, stream);   // header: Mcnt/done/argKey/Scnt

    k_init<<<dim3((NN + 255) / 256, BDIM), 256, 0, stream>>>(
        logits, scores, parent, compKey, selIdx, Mcnt, argKey, done);
    k_tobf<<<dim3((NDIM + 3) / 4, BDIM), 256, 0, stream>>>(sig, selIdx, Mcnt, Xf8);
    k_sim_mfma<<<NT128 * BDIM, 256, 32768, stream>>>(Xf8, selIdx, Mcnt, parent);
    k_comp<<<BDIM, 1024, 0, stream>>>(parent, selIdx, Mcnt, scores, compKey, seedNode, Scnt);
    k_write<<<dim3(NDIM / 4, BDIM), 256, 0, stream>>>(sig, scores, seedNode, Scnt, out);
}